// Round 1
// baseline (4422.743 us; speedup 1.0000x reference)
//
#include <hip/hip_runtime.h>
#include <hip/hip_bf16.h>
#include <math.h>

// Problem constants
#define N_      4
#define L_      256
#define M_      2
#define D_      768
#define H_      12
#define FF_     3072
#define DH_     64
#define LAYERS_ 4
#define BASE_   8          // N*M
#define T_      1032       // BASE_ + N*L
#define KK_     258        // M + L

// ---------------------------------------------------------------------------
// x[row] = (row<8 ? memory[row] + pos[row%2] : emb[ids[row-8]] + pos[2 + l])
// ---------------------------------------------------------------------------
__global__ __launch_bounds__(256) void embed_kernel(
    const int* __restrict__ ids, const float* __restrict__ memory,
    const float* __restrict__ emb, const float* __restrict__ pos,
    float* __restrict__ x) {
  int row = blockIdx.x;
  const float *src, *p;
  if (row < BASE_) {
    src = memory + (long long)row * D_;
    p   = pos + (row & 1) * D_;
  } else {
    int i = row - BASE_;
    int tok = ids[i];
    src = emb + (long long)tok * D_;
    p   = pos + (M_ + (i & (L_ - 1))) * D_;
  }
  for (int d = threadIdx.x; d < D_; d += 256)
    x[(long long)row * D_ + d] = src[d] + p[d];
}

// ---------------------------------------------------------------------------
// C[M,N] = A[M,K] @ B[K,N] + bias ; ACT==1 -> exact GELU
// block = 256 threads, 64x64 C tile, 4x4 per-thread micro-tile, K-tile = 16
// ---------------------------------------------------------------------------
template <int ACT>
__global__ __launch_bounds__(256) void gemm_kernel(
    const float* __restrict__ A, const float* __restrict__ B,
    const float* __restrict__ bias, float* __restrict__ C,
    int M, int N, int K) {
  __shared__ float As[64][17];   // +1 pad breaks bank conflicts on column reads
  __shared__ float Bs[16][64];
  const int tid = threadIdx.x;
  const int tx = tid & 15, ty = tid >> 4;
  const int col0 = blockIdx.x * 64;
  const int row0 = blockIdx.y * 64;

  float acc[4][4] = {};
  for (int k0 = 0; k0 < K; k0 += 16) {
    #pragma unroll
    for (int i = tid; i < 64 * 16; i += 256) {
      int r = i >> 4, c = i & 15;
      int gr = row0 + r;
      As[r][c] = (gr < M) ? A[(long long)gr * K + k0 + c] : 0.f;
    }
    #pragma unroll
    for (int i = tid; i < 16 * 64; i += 256) {
      int r = i >> 6, c = i & 63;
      Bs[r][c] = B[(long long)(k0 + r) * N + col0 + c];  // K,N multiples of 64
    }
    __syncthreads();
    #pragma unroll
    for (int kk = 0; kk < 16; ++kk) {
      float a[4], b[4];
      #pragma unroll
      for (int i = 0; i < 4; ++i) a[i] = As[ty * 4 + i][kk];
      #pragma unroll
      for (int j = 0; j < 4; ++j) b[j] = Bs[kk][tx * 4 + j];
      #pragma unroll
      for (int i = 0; i < 4; ++i)
        #pragma unroll
        for (int j = 0; j < 4; ++j) acc[i][j] += a[i] * b[j];
    }
    __syncthreads();
  }
  #pragma unroll
  for (int i = 0; i < 4; ++i) {
    int r = row0 + ty * 4 + i;
    if (r >= M) break;
    #pragma unroll
    for (int j = 0; j < 4; ++j) {
      int c = col0 + tx * 4 + j;
      float v = acc[i][j] + bias[c];
      if (ACT == 1) v = 0.5f * v * (1.f + erff(v * 0.70710678118654752f));
      C[(long long)r * N + c] = v;
    }
  }
}

// ---------------------------------------------------------------------------
// Attention: one block per token t. All heads. Keys = 258 tokens of t's batch.
// ---------------------------------------------------------------------------
__global__ __launch_bounds__(256) void attn_kernel(
    const float* __restrict__ q, const float* __restrict__ kf,
    const float* __restrict__ vf, float* __restrict__ ctx) {
  __shared__ float qs[D_];
  __shared__ float ss[H_ * KK_];   // 3096 scores
  __shared__ float sinv[H_];
  const int t = blockIdx.x;
  const int tid = threadIdx.x;
  const int b = (t < BASE_) ? (t >> 1) : ((t - BASE_) >> 8);

  for (int d = tid; d < D_; d += 256) qs[d] = q[(long long)t * D_ + d];
  __syncthreads();

  // scores[h][k] = (q[t,h,:] . k[g(k),h,:]) / 8
  for (int e = tid; e < H_ * KK_; e += 256) {
    int h = e / KK_, kk = e - h * KK_;
    int g = (kk < M_) ? (b * M_ + kk) : (BASE_ + b * L_ + (kk - M_));
    const float* kr = kf + (long long)g * D_ + h * DH_;
    const float* qh = qs + h * DH_;
    float acc = 0.f;
    #pragma unroll
    for (int d = 0; d < DH_; ++d) acc += qh[d] * kr[d];
    ss[e] = acc * 0.125f;   // 1/sqrt(64)
  }
  __syncthreads();

  // per-head softmax (12 threads, serial over 258 — small)
  if (tid < H_) {
    float mx = -1e30f;
    for (int kk = 0; kk < KK_; ++kk) mx = fmaxf(mx, ss[tid * KK_ + kk]);
    float sum = 0.f;
    for (int kk = 0; kk < KK_; ++kk) {
      float p = expf(ss[tid * KK_ + kk] - mx);
      ss[tid * KK_ + kk] = p;
      sum += p;
    }
    sinv[tid] = 1.f / sum;
  }
  __syncthreads();

  // ctx[t, dg] = sum_k p[h][k] * v[g(k), dg]   (lanes coalesced over dg)
  for (int dg = tid; dg < D_; dg += 256) {
    int h = dg >> 6;
    float acc = 0.f;
    for (int kk = 0; kk < KK_; ++kk) {
      int g = (kk < M_) ? (b * M_ + kk) : (BASE_ + b * L_ + (kk - M_));
      acc += ss[h * KK_ + kk] * vf[(long long)g * D_ + dg];
    }
    ctx[(long long)t * D_ + dg] = acc * sinv[h];
  }
}

// ---------------------------------------------------------------------------
// x = LayerNorm(x + delta) * g + b   (in-place on x; one block per row)
// ---------------------------------------------------------------------------
__global__ __launch_bounds__(256) void add_ln_kernel(
    float* __restrict__ x, const float* __restrict__ delta,
    const float* __restrict__ g, const float* __restrict__ b) {
  __shared__ float sred[4];
  __shared__ float sbc;
  const int t = blockIdx.x, tid = threadIdx.x;
  float y[3];
  float s = 0.f;
  #pragma unroll
  for (int i = 0; i < 3; ++i) {
    int d = tid + i * 256;
    y[i] = x[(long long)t * D_ + d] + delta[(long long)t * D_ + d];
    s += y[i];
  }
  // mean
  #pragma unroll
  for (int o = 32; o > 0; o >>= 1) s += __shfl_down(s, o);
  if ((tid & 63) == 0) sred[tid >> 6] = s;
  __syncthreads();
  if (tid == 0) sbc = (sred[0] + sred[1] + sred[2] + sred[3]) * (1.f / D_);
  __syncthreads();
  const float mu = sbc;
  __syncthreads();
  // var
  float vs = 0.f;
  #pragma unroll
  for (int i = 0; i < 3; ++i) { float d = y[i] - mu; vs += d * d; }
  #pragma unroll
  for (int o = 32; o > 0; o >>= 1) vs += __shfl_down(vs, o);
  if ((tid & 63) == 0) sred[tid >> 6] = vs;
  __syncthreads();
  if (tid == 0) sbc = (sred[0] + sred[1] + sred[2] + sred[3]) * (1.f / D_);
  __syncthreads();
  const float inv = rsqrtf(sbc + 1e-5f);
  #pragma unroll
  for (int i = 0; i < 3; ++i) {
    int d = tid + i * 256;
    x[(long long)t * D_ + d] = (y[i] - mu) * inv * g[d] + b[d];
  }
}

// ---------------------------------------------------------------------------
// out = x[8:1032]  (contiguous)
// ---------------------------------------------------------------------------
__global__ __launch_bounds__(256) void out_copy_kernel(
    const float* __restrict__ x, float* __restrict__ out, int n) {
  int i = blockIdx.x * 256 + threadIdx.x;
  if (i < n) out[i] = x[BASE_ * D_ + i];
}

// ---------------------------------------------------------------------------
extern "C" void kernel_launch(void* const* d_in, const int* in_sizes, int n_in,
                              void* d_out, int out_size, void* d_ws, size_t ws_size,
                              hipStream_t stream) {
  const int*   ids    = (const int*)  d_in[0];
  const float* memory = (const float*)d_in[1];
  const float* emb    = (const float*)d_in[2];
  const float* pos    = (const float*)d_in[3];
  const float* Wq     = (const float*)d_in[4];
  const float* bq     = (const float*)d_in[5];
  const float* Wk     = (const float*)d_in[6];
  const float* bk     = (const float*)d_in[7];
  const float* Wv     = (const float*)d_in[8];
  const float* bv     = (const float*)d_in[9];
  const float* W1     = (const float*)d_in[10];
  const float* b1     = (const float*)d_in[11];
  const float* W2     = (const float*)d_in[12];
  const float* b2     = (const float*)d_in[13];
  const float* g1     = (const float*)d_in[14];
  const float* be1    = (const float*)d_in[15];
  const float* g2     = (const float*)d_in[16];
  const float* be2    = (const float*)d_in[17];

  float* ws = (float*)d_ws;
  float* x  = ws;                    // T*D
  float* qb = x  + (size_t)T_ * D_;  // T*D
  float* kb = qb + (size_t)T_ * D_;  // T*D
  float* vb = kb + (size_t)T_ * D_;  // T*D
  float* cb = vb + (size_t)T_ * D_;  // T*D (ctx / ffn delta)
  float* hb = cb + (size_t)T_ * D_;  // T*FF

  embed_kernel<<<T_, 256, 0, stream>>>(ids, memory, emb, pos, x);

  const dim3 gQKV(D_ / 64, (T_ + 63) / 64);   // 12 x 17
  const dim3 gFF1(FF_ / 64, (T_ + 63) / 64);  // 48 x 17

  for (int i = 0; i < LAYERS_; ++i) {
    const long long wo  = (long long)i * D_ * D_;
    const long long wo1 = (long long)i * D_ * FF_;
    gemm_kernel<0><<<gQKV, 256, 0, stream>>>(x, Wq + wo, bq + i * D_, qb, T_, D_, D_);
    gemm_kernel<0><<<gQKV, 256, 0, stream>>>(x, Wk + wo, bk + i * D_, kb, T_, D_, D_);
    gemm_kernel<0><<<gQKV, 256, 0, stream>>>(x, Wv + wo, bv + i * D_, vb, T_, D_, D_);
    attn_kernel<<<T_, 256, 0, stream>>>(qb, kb, vb, cb);
    add_ln_kernel<<<T_, 256, 0, stream>>>(x, cb, g1 + i * D_, be1 + i * D_);
    gemm_kernel<1><<<gFF1, 256, 0, stream>>>(x, W1 + wo1, b1 + i * FF_, hb, T_, FF_, D_);
    gemm_kernel<0><<<gQKV, 256, 0, stream>>>(hb, W2 + wo1, b2 + i * D_, cb, T_, D_, FF_);
    add_ln_kernel<<<T_, 256, 0, stream>>>(x, cb, g2 + i * D_, be2 + i * D_);
  }

  out_copy_kernel<<<(out_size + 255) / 256, 256, 0, stream>>>(x, (float*)d_out, out_size);
}

// Round 2
// 1328.520 us; speedup vs baseline: 3.3291x; 3.3291x over previous
//
#include <hip/hip_runtime.h>
#include <hip/hip_bf16.h>
#include <math.h>

// Problem constants
#define N_      4
#define L_      256
#define M_      2
#define D_      768
#define H_      12
#define FF_     3072
#define DH_     64
#define LAYERS_ 4
#define BASE_   8          // N*M
#define T_      1032       // BASE_ + N*L
#define TP_     1088       // T_ padded to multiple of 64 (pad rows hold poison; never consumed)
#define KK_     258        // M + L
#define QS_     2304       // fused q|k|v row stride

typedef __bf16 bf16x8 __attribute__((ext_vector_type(8)));
typedef float  f32x4  __attribute__((ext_vector_type(4)));

// Async global->LDS, 16B per lane. LDS dest is wave-uniform base + lane*16.
__device__ __forceinline__ void async_load16(const __hip_bfloat16* g, __hip_bfloat16* l) {
  __builtin_amdgcn_global_load_lds(
      (const __attribute__((address_space(1))) unsigned int*)g,
      (__attribute__((address_space(3))) unsigned int*)l, 16, 0, 0);
}

// ---------------------------------------------------------------------------
// dst[N,K] bf16 = cast(transpose(src[K,N] fp32)). K,N multiples of 32.
// ---------------------------------------------------------------------------
__global__ __launch_bounds__(256) void transpose_cast_kernel(
    const float* __restrict__ src, __hip_bfloat16* __restrict__ dst, int K, int N) {
  __shared__ float tile[32][33];
  const int k0 = blockIdx.y * 32, n0 = blockIdx.x * 32;
  const int r = threadIdx.x >> 5, c = threadIdx.x & 31;
  #pragma unroll
  for (int i = 0; i < 4; ++i)
    tile[r + i * 8][c] = src[(size_t)(k0 + r + i * 8) * N + n0 + c];
  __syncthreads();
  #pragma unroll
  for (int i = 0; i < 4; ++i)
    dst[(size_t)(n0 + r + i * 8) * K + k0 + c] = __float2bfloat16(tile[c][r + i * 8]);
}

// bqkv[l][0:768]=bq[l], [768:1536]=bk[l], [1536:2304]=bv[l]
__global__ __launch_bounds__(256) void pack_bias_kernel(
    const float* __restrict__ bq, const float* __restrict__ bk,
    const float* __restrict__ bv, float* __restrict__ out) {
  int i = blockIdx.x * 256 + threadIdx.x;          // grid covers LAYERS_*QS_
  int l = i / QS_, j = i - l * QS_;
  float v;
  if (j < D_)            v = bq[l * D_ + j];
  else if (j < 2 * D_)   v = bk[l * D_ + (j - D_)];
  else                   v = bv[l * D_ + (j - 2 * D_)];
  out[i] = v;
}

// ---------------------------------------------------------------------------
// x[row] (fp32) and xb[row] (bf16) from memory/embedding + positional
// ---------------------------------------------------------------------------
__global__ __launch_bounds__(256) void embed_kernel(
    const int* __restrict__ ids, const float* __restrict__ memory,
    const float* __restrict__ emb, const float* __restrict__ pos,
    float* __restrict__ x, __hip_bfloat16* __restrict__ xb) {
  int row = blockIdx.x;
  const float *src, *p;
  if (row < BASE_) {
    src = memory + (long long)row * D_;
    p   = pos + (row & 1) * D_;
  } else {
    int i = row - BASE_;
    int tok = ids[i];
    src = emb + (long long)tok * D_;
    p   = pos + (M_ + (i & (L_ - 1))) * D_;
  }
  for (int d = threadIdx.x; d < D_; d += 256) {
    float v = src[d] + p[d];
    x[(long long)row * D_ + d]  = v;
    xb[(long long)row * D_ + d] = __float2bfloat16(v);
  }
}

// ---------------------------------------------------------------------------
// C[M,N] (+bias, opt GELU) = A[MP,K]bf16 @ Bt[N,K]bf16^T
// 64x64 block tile, BK=128 (4 slabs of 32), 4 waves 2x2, wave=32x32,
// 16 mfma_16x16x32 per barrier pair per wave. N%64==0, K%128==0.
// ---------------------------------------------------------------------------
template <int ACT, int WF32, int WBF16>
__global__ __launch_bounds__(256) void gemm_mfma(
    const __hip_bfloat16* __restrict__ A,   // [MP,K]
    const __hip_bfloat16* __restrict__ Bt,  // [N,K]
    const float* __restrict__ bias,         // [N]
    float* __restrict__ C,                  // [MP,N] if WF32
    __hip_bfloat16* __restrict__ Cb,        // [MP,N] if WBF16
    int N, int K) {
  __shared__ __align__(16) __hip_bfloat16 As[4][64][32];
  __shared__ __align__(16) __hip_bfloat16 Bs[4][64][32];
  const int tid  = threadIdx.x;
  const int lane = tid & 63, wid = tid >> 6;
  const int ln   = lane & 15, qd = lane >> 4;
  const int wm   = wid >> 1, wn = wid & 1;

  // staging addresses: wave wid covers rows wid*16..wid*16+15 of each slab;
  // lane covers row wid*16 + lane/4, cols (lane&3)*8..+7 (16B)
  const size_t arow = (size_t)(blockIdx.y * 64 + wid * 16 + (lane >> 2)) * K + (lane & 3) * 8;
  const size_t brow = (size_t)(blockIdx.x * 64 + wid * 16 + (lane >> 2)) * K + (lane & 3) * 8;

  f32x4 acc[2][2] = {};
  for (int k0 = 0; k0 < K; k0 += 128) {
    #pragma unroll
    for (int s = 0; s < 4; ++s) {
      async_load16(A  + arow + k0 + s * 32, &As[s][wid * 16][0]);
      async_load16(Bt + brow + k0 + s * 32, &Bs[s][wid * 16][0]);
    }
    __syncthreads();
    #pragma unroll
    for (int s = 0; s < 4; ++s) {
      bf16x8 a0 = *(const bf16x8*)&As[s][wm * 32 + ln][qd * 8];
      bf16x8 a1 = *(const bf16x8*)&As[s][wm * 32 + 16 + ln][qd * 8];
      bf16x8 b0 = *(const bf16x8*)&Bs[s][wn * 32 + ln][qd * 8];
      bf16x8 b1 = *(const bf16x8*)&Bs[s][wn * 32 + 16 + ln][qd * 8];
      acc[0][0] = __builtin_amdgcn_mfma_f32_16x16x32_bf16(a0, b0, acc[0][0], 0, 0, 0);
      acc[0][1] = __builtin_amdgcn_mfma_f32_16x16x32_bf16(a0, b1, acc[0][1], 0, 0, 0);
      acc[1][0] = __builtin_amdgcn_mfma_f32_16x16x32_bf16(a1, b0, acc[1][0], 0, 0, 0);
      acc[1][1] = __builtin_amdgcn_mfma_f32_16x16x32_bf16(a1, b1, acc[1][1], 0, 0, 0);
    }
    __syncthreads();
  }
  // epilogue: C/D layout col=lane&15, row=(lane>>4)*4+reg
  #pragma unroll
  for (int mt = 0; mt < 2; ++mt) {
    #pragma unroll
    for (int nt = 0; nt < 2; ++nt) {
      const int col = blockIdx.x * 64 + wn * 32 + nt * 16 + ln;
      const float bv = bias[col];
      #pragma unroll
      for (int i = 0; i < 4; ++i) {
        const int row = blockIdx.y * 64 + wm * 32 + mt * 16 + qd * 4 + i;
        float v = acc[mt][nt][i] + bv;
        if (ACT) v = 0.5f * v * (1.f + erff(v * 0.70710678118654752f));
        if (WF32)  C[(size_t)row * N + col]  = v;
        if (WBF16) Cb[(size_t)row * N + col] = __float2bfloat16(v);
      }
    }
  }
}

// ---------------------------------------------------------------------------
// Attention: one block per token t, fused qkv buffer (row stride QS_)
// ---------------------------------------------------------------------------
__global__ __launch_bounds__(256) void attn_kernel(
    const float* __restrict__ qkv, float* __restrict__ ctx) {
  __shared__ float qs[D_];
  __shared__ float ss[H_ * KK_];   // 3096 scores
  __shared__ float sinv[H_];
  const int t = blockIdx.x;
  const int tid = threadIdx.x;
  const int b = (t < BASE_) ? (t >> 1) : ((t - BASE_) >> 8);

  for (int d = tid; d < D_; d += 256) qs[d] = qkv[(long long)t * QS_ + d];
  __syncthreads();

  for (int e = tid; e < H_ * KK_; e += 256) {
    int h = e / KK_, kk = e - h * KK_;
    int g = (kk < M_) ? (b * M_ + kk) : (BASE_ + b * L_ + (kk - M_));
    const float* kr = qkv + (long long)g * QS_ + D_ + h * DH_;
    const float* qh = qs + h * DH_;
    float acc = 0.f;
    #pragma unroll
    for (int d = 0; d < DH_; ++d) acc += qh[d] * kr[d];
    ss[e] = acc * 0.125f;   // 1/sqrt(64)
  }
  __syncthreads();

  if (tid < H_) {
    float mx = -1e30f;
    for (int kk = 0; kk < KK_; ++kk) mx = fmaxf(mx, ss[tid * KK_ + kk]);
    float sum = 0.f;
    for (int kk = 0; kk < KK_; ++kk) {
      float p = expf(ss[tid * KK_ + kk] - mx);
      ss[tid * KK_ + kk] = p;
      sum += p;
    }
    sinv[tid] = 1.f / sum;
  }
  __syncthreads();

  for (int dg = tid; dg < D_; dg += 256) {
    int h = dg >> 6;
    float acc = 0.f;
    for (int kk = 0; kk < KK_; ++kk) {
      int g = (kk < M_) ? (b * M_ + kk) : (BASE_ + b * L_ + (kk - M_));
      acc += ss[h * KK_ + kk] * qkv[(long long)g * QS_ + 2 * D_ + dg];
    }
    ctx[(long long)t * D_ + dg] = acc * sinv[h];
  }
}

// ---------------------------------------------------------------------------
// x = LayerNorm(x + delta)*g + b  (fp32, in-place) ; also emits xb (bf16)
// ---------------------------------------------------------------------------
__global__ __launch_bounds__(256) void add_ln_kernel(
    float* __restrict__ x, const float* __restrict__ delta,
    const float* __restrict__ g, const float* __restrict__ b,
    __hip_bfloat16* __restrict__ xb) {
  __shared__ float sred[4];
  __shared__ float sbc;
  const int t = blockIdx.x, tid = threadIdx.x;
  float y[3];
  float s = 0.f;
  #pragma unroll
  for (int i = 0; i < 3; ++i) {
    int d = tid + i * 256;
    y[i] = x[(long long)t * D_ + d] + delta[(long long)t * D_ + d];
    s += y[i];
  }
  #pragma unroll
  for (int o = 32; o > 0; o >>= 1) s += __shfl_down(s, o);
  if ((tid & 63) == 0) sred[tid >> 6] = s;
  __syncthreads();
  if (tid == 0) sbc = (sred[0] + sred[1] + sred[2] + sred[3]) * (1.f / D_);
  __syncthreads();
  const float mu = sbc;
  __syncthreads();
  float vs = 0.f;
  #pragma unroll
  for (int i = 0; i < 3; ++i) { float d = y[i] - mu; vs += d * d; }
  #pragma unroll
  for (int o = 32; o > 0; o >>= 1) vs += __shfl_down(vs, o);
  if ((tid & 63) == 0) sred[tid >> 6] = vs;
  __syncthreads();
  if (tid == 0) sbc = (sred[0] + sred[1] + sred[2] + sred[3]) * (1.f / D_);
  __syncthreads();
  const float inv = rsqrtf(sbc + 1e-5f);
  #pragma unroll
  for (int i = 0; i < 3; ++i) {
    int d = tid + i * 256;
    float v = (y[i] - mu) * inv * g[d] + b[d];
    x[(long long)t * D_ + d]  = v;
    xb[(long long)t * D_ + d] = __float2bfloat16(v);
  }
}

__global__ __launch_bounds__(256) void out_copy_kernel(
    const float* __restrict__ x, float* __restrict__ out, int n) {
  int i = blockIdx.x * 256 + threadIdx.x;
  if (i < n) out[i] = x[BASE_ * D_ + i];
}

// ---------------------------------------------------------------------------
extern "C" void kernel_launch(void* const* d_in, const int* in_sizes, int n_in,
                              void* d_out, int out_size, void* d_ws, size_t ws_size,
                              hipStream_t stream) {
  const int*   ids    = (const int*)  d_in[0];
  const float* memory = (const float*)d_in[1];
  const float* emb    = (const float*)d_in[2];
  const float* pos    = (const float*)d_in[3];
  const float* Wq     = (const float*)d_in[4];
  const float* bq     = (const float*)d_in[5];
  const float* Wk     = (const float*)d_in[6];
  const float* bk     = (const float*)d_in[7];
  const float* Wv     = (const float*)d_in[8];
  const float* bv     = (const float*)d_in[9];
  const float* W1     = (const float*)d_in[10];
  const float* b1     = (const float*)d_in[11];
  const float* W2     = (const float*)d_in[12];
  const float* b2     = (const float*)d_in[13];
  const float* g1     = (const float*)d_in[14];
  const float* be1    = (const float*)d_in[15];
  const float* g2     = (const float*)d_in[16];
  const float* be2    = (const float*)d_in[17];

  // workspace layout (byte offsets; all sizes 256B-multiples)
  char* w = (char*)d_ws;
  float* x    = (float*)w;                      w += (size_t)TP_ * D_ * 4;    // fp32 activations
  float* qkv  = (float*)w;                      w += (size_t)TP_ * QS_ * 4;
  float* cb   = (float*)w;                      w += (size_t)TP_ * D_ * 4;
  float* bqkv = (float*)w;                      w += (size_t)LAYERS_ * QS_ * 4;
  __hip_bfloat16* xb    = (__hip_bfloat16*)w;   w += (size_t)TP_ * D_ * 2;
  __hip_bfloat16* hbb   = (__hip_bfloat16*)w;   w += (size_t)TP_ * FF_ * 2;
  __hip_bfloat16* Wqkvt = (__hip_bfloat16*)w;   w += (size_t)LAYERS_ * QS_ * D_ * 2; // [l][n=2304][k=768]
  __hip_bfloat16* W1t   = (__hip_bfloat16*)w;   w += (size_t)LAYERS_ * FF_ * D_ * 2; // [l][n=3072][k=768]
  __hip_bfloat16* W2t   = (__hip_bfloat16*)w;   w += (size_t)LAYERS_ * D_ * FF_ * 2; // [l][n=768][k=3072]

  // --- weight conversion (transpose + cast), once per call ---
  for (int i = 0; i < LAYERS_; ++i) {
    const size_t wo  = (size_t)i * D_ * D_;
    const size_t wo1 = (size_t)i * D_ * FF_;
    __hip_bfloat16* dqkv = Wqkvt + (size_t)i * QS_ * D_;
    transpose_cast_kernel<<<dim3(D_ / 32, D_ / 32), 256, 0, stream>>>(Wq + wo, dqkv,                        D_, D_);
    transpose_cast_kernel<<<dim3(D_ / 32, D_ / 32), 256, 0, stream>>>(Wk + wo, dqkv + (size_t)D_ * D_,      D_, D_);
    transpose_cast_kernel<<<dim3(D_ / 32, D_ / 32), 256, 0, stream>>>(Wv + wo, dqkv + (size_t)2 * D_ * D_,  D_, D_);
    transpose_cast_kernel<<<dim3(FF_ / 32, D_ / 32), 256, 0, stream>>>(W1 + wo1, W1t + (size_t)i * FF_ * D_, D_, FF_);
    transpose_cast_kernel<<<dim3(D_ / 32, FF_ / 32), 256, 0, stream>>>(W2 + wo1, W2t + (size_t)i * D_ * FF_, FF_, D_);
  }
  pack_bias_kernel<<<LAYERS_ * QS_ / 256, 256, 0, stream>>>(bq, bk, bv, bqkv);

  embed_kernel<<<T_, 256, 0, stream>>>(ids, memory, emb, pos, x, xb);

  for (int i = 0; i < LAYERS_; ++i) {
    gemm_mfma<0, 1, 0><<<dim3(QS_ / 64, TP_ / 64), 256, 0, stream>>>(
        xb, Wqkvt + (size_t)i * QS_ * D_, bqkv + i * QS_, qkv, nullptr, QS_, D_);
    attn_kernel<<<T_, 256, 0, stream>>>(qkv, cb);
    add_ln_kernel<<<T_, 256, 0, stream>>>(x, cb, g1 + i * D_, be1 + i * D_, xb);
    gemm_mfma<1, 0, 1><<<dim3(FF_ / 64, TP_ / 64), 256, 0, stream>>>(
        xb, W1t + (size_t)i * FF_ * D_, b1 + i * FF_, nullptr, hbb, FF_, D_);
    gemm_mfma<0, 1, 0><<<dim3(D_ / 64, TP_ / 64), 256, 0, stream>>>(
        hbb, W2t + (size_t)i * D_ * FF_, b2 + i * D_, cb, nullptr, D_, FF_);
    add_ln_kernel<<<T_, 256, 0, stream>>>(x, cb, g2 + i * D_, be2 + i * D_, xb);
  }

  out_copy_kernel<<<(out_size + 255) / 256, 256, 0, stream>>>(x, (float*)d_out, out_size);
}

// Round 3
// 601.223 us; speedup vs baseline: 7.3562x; 2.2097x over previous
//
#include <hip/hip_runtime.h>
#include <hip/hip_bf16.h>
#include <math.h>

// Problem constants
#define N_      4
#define L_      256
#define M_      2
#define D_      768
#define H_      12
#define FF_     3072
#define DH_     64
#define LAYERS_ 4
#define BASE_   8          // N*M
#define T_      1032       // BASE_ + N*L
#define TP_     1088       // T_ padded to multiple of 64
#define KK_     258        // M + L
#define QS_     2304       // fused q|k|v row stride
#define PS_     264        // P LDS row stride (bf16): 264*2/4=132%32=4 -> 2-way (free)

typedef __bf16 bf16x8 __attribute__((ext_vector_type(8)));
typedef float  f32x4  __attribute__((ext_vector_type(4)));

__device__ __forceinline__ void async_load16(const __hip_bfloat16* g, __hip_bfloat16* l) {
  __builtin_amdgcn_global_load_lds(
      (const __attribute__((address_space(1))) unsigned int*)g,
      (__attribute__((address_space(3))) unsigned int*)l, 16, 0, 0);
}

// ---------------------------------------------------------------------------
// dst[N,K] bf16 = cast(transpose(src[K,N] fp32)). K,N multiples of 32.
// ---------------------------------------------------------------------------
__global__ __launch_bounds__(256) void transpose_cast_kernel(
    const float* __restrict__ src, __hip_bfloat16* __restrict__ dst, int K, int N) {
  __shared__ float tile[32][33];
  const int k0 = blockIdx.y * 32, n0 = blockIdx.x * 32;
  const int r = threadIdx.x >> 5, c = threadIdx.x & 31;
  #pragma unroll
  for (int i = 0; i < 4; ++i)
    tile[r + i * 8][c] = src[(size_t)(k0 + r + i * 8) * N + n0 + c];
  __syncthreads();
  #pragma unroll
  for (int i = 0; i < 4; ++i)
    dst[(size_t)(n0 + r + i * 8) * K + k0 + c] = __float2bfloat16(tile[c][r + i * 8]);
}

__global__ __launch_bounds__(256) void pack_bias_kernel(
    const float* __restrict__ bq, const float* __restrict__ bk,
    const float* __restrict__ bv, float* __restrict__ out) {
  int i = blockIdx.x * 256 + threadIdx.x;
  int l = i / QS_, j = i - l * QS_;
  float v;
  if (j < D_)            v = bq[l * D_ + j];
  else if (j < 2 * D_)   v = bk[l * D_ + (j - D_)];
  else                   v = bv[l * D_ + (j - 2 * D_)];
  out[i] = v;
}

// ---------------------------------------------------------------------------
__global__ __launch_bounds__(256) void embed_kernel(
    const int* __restrict__ ids, const float* __restrict__ memory,
    const float* __restrict__ emb, const float* __restrict__ pos,
    float* __restrict__ x, __hip_bfloat16* __restrict__ xb) {
  int row = blockIdx.x;
  const float *src, *p;
  if (row < BASE_) {
    src = memory + (long long)row * D_;
    p   = pos + (row & 1) * D_;
  } else {
    int i = row - BASE_;
    int tok = ids[i];
    src = emb + (long long)tok * D_;
    p   = pos + (M_ + (i & (L_ - 1))) * D_;
  }
  for (int d = threadIdx.x; d < D_; d += 256) {
    float v = src[d] + p[d];
    x[(long long)row * D_ + d]  = v;
    xb[(long long)row * D_ + d] = __float2bfloat16(v);
  }
}

// ---------------------------------------------------------------------------
// C = A[MP,K] @ Bt[N,K]^T + bias (opt GELU). 64x64 tile, BK=128, 4 waves 2x2.
// WVT: cols>=1536 go transposed to vt[col-1536][row] (V section of QKV gemm).
// ---------------------------------------------------------------------------
template <int ACT, int WF32, int WBF16, int WVT>
__global__ __launch_bounds__(256) void gemm_mfma(
    const __hip_bfloat16* __restrict__ A,   // [MP,K]
    const __hip_bfloat16* __restrict__ Bt,  // [N,K]
    const float* __restrict__ bias,         // [N]
    float* __restrict__ C,                  // fp32 out
    __hip_bfloat16* __restrict__ Cb,        // bf16 out
    __hip_bfloat16* __restrict__ vt,        // [768][TP_] transposed V out
    int N, int K) {
  __shared__ __align__(16) __hip_bfloat16 As[4][64][32];
  __shared__ __align__(16) __hip_bfloat16 Bs[4][64][32];
  const int tid  = threadIdx.x;
  const int lane = tid & 63, wid = tid >> 6;
  const int ln   = lane & 15, qd = lane >> 4;
  const int wm   = wid >> 1, wn = wid & 1;

  const size_t arow = (size_t)(blockIdx.y * 64 + wid * 16 + (lane >> 2)) * K + (lane & 3) * 8;
  const size_t brow = (size_t)(blockIdx.x * 64 + wid * 16 + (lane >> 2)) * K + (lane & 3) * 8;

  f32x4 acc[2][2] = {};
  for (int k0 = 0; k0 < K; k0 += 128) {
    #pragma unroll
    for (int s = 0; s < 4; ++s) {
      async_load16(A  + arow + k0 + s * 32, &As[s][wid * 16][0]);
      async_load16(Bt + brow + k0 + s * 32, &Bs[s][wid * 16][0]);
    }
    __syncthreads();
    #pragma unroll
    for (int s = 0; s < 4; ++s) {
      bf16x8 a0 = *(const bf16x8*)&As[s][wm * 32 + ln][qd * 8];
      bf16x8 a1 = *(const bf16x8*)&As[s][wm * 32 + 16 + ln][qd * 8];
      bf16x8 b0 = *(const bf16x8*)&Bs[s][wn * 32 + ln][qd * 8];
      bf16x8 b1 = *(const bf16x8*)&Bs[s][wn * 32 + 16 + ln][qd * 8];
      acc[0][0] = __builtin_amdgcn_mfma_f32_16x16x32_bf16(a0, b0, acc[0][0], 0, 0, 0);
      acc[0][1] = __builtin_amdgcn_mfma_f32_16x16x32_bf16(a0, b1, acc[0][1], 0, 0, 0);
      acc[1][0] = __builtin_amdgcn_mfma_f32_16x16x32_bf16(a1, b0, acc[1][0], 0, 0, 0);
      acc[1][1] = __builtin_amdgcn_mfma_f32_16x16x32_bf16(a1, b1, acc[1][1], 0, 0, 0);
    }
    __syncthreads();
  }
  #pragma unroll
  for (int mt = 0; mt < 2; ++mt) {
    #pragma unroll
    for (int nt = 0; nt < 2; ++nt) {
      const int col = blockIdx.x * 64 + wn * 32 + nt * 16 + ln;
      const float bv = bias[col];
      #pragma unroll
      for (int i = 0; i < 4; ++i) {
        const int row = blockIdx.y * 64 + wm * 32 + mt * 16 + qd * 4 + i;
        float v = acc[mt][nt][i] + bv;
        if (ACT) v = 0.5f * v * (1.f + erff(v * 0.70710678118654752f));
        if (WF32)  C[(size_t)row * N + col]  = v;
        if (WVT) {
          if (col < 2 * D_) Cb[(size_t)row * N + col] = __float2bfloat16(v);
          else              vt[(size_t)(col - 2 * D_) * TP_ + row] = __float2bfloat16(v);
        } else if (WBF16) {
          Cb[(size_t)row * N + col] = __float2bfloat16(v);
        }
      }
    }
  }
}

// ---------------------------------------------------------------------------
// MFMA attention. grid = (5 q-tiles, 12 heads, 4 batches), 4 waves/block.
// Key ordering: col 0..255 = seq tokens, 256/257 = memory tokens, >=258 pad.
// No barriers: K,V^T,Q frags read straight from global; only P round-trips
// LDS (wave-private rows).
// ---------------------------------------------------------------------------
__global__ __launch_bounds__(256) void attn_mfma(
    const __hip_bfloat16* __restrict__ qkv,  // [TP_][QS_]
    const __hip_bfloat16* __restrict__ vtb,  // [768][TP_]
    float* __restrict__ ctx) {               // [TP_][D_]
  __shared__ __align__(16) __hip_bfloat16 Ps[64][PS_];
  const int qt = blockIdx.x, h = blockIdx.y, b = blockIdx.z;
  const int tid = threadIdx.x;
  const int w = tid >> 6, lane = tid & 63, ln = lane & 15, qd = lane >> 4;

  // Q fragments (A operand): m=ln -> q-row w*16+ln of this tile
  bf16x8 aq0, aq1;
  {
    int j = qt * 64 + w * 16 + ln;
    int tok = (j < 256) ? (BASE_ + b * L_ + j)
            : ((j < KK_) ? (b * M_ + (j - 256)) : (b * M_));
    const __hip_bfloat16* qp = qkv + (size_t)tok * QS_ + h * DH_ + qd * 8;
    aq0 = *(const bf16x8*)qp;
    aq1 = *(const bf16x8*)(qp + 32);
  }

  // S = Q K^T over 17 key-tiles of 16
  f32x4 sa[17];
  #pragma unroll
  for (int nt = 0; nt < 17; ++nt) sa[nt] = (f32x4){0.f, 0.f, 0.f, 0.f};
  #pragma unroll
  for (int nt = 0; nt < 17; ++nt) {
    int key = nt * 16 + ln;
    int ktok = (key < 256) ? (BASE_ + b * L_ + key)
             : ((key < KK_) ? (b * M_ + (key - 256)) : (b * M_));
    const __hip_bfloat16* kp = qkv + (size_t)ktok * QS_ + D_ + h * DH_ + qd * 8;
    bf16x8 b0 = *(const bf16x8*)kp;
    bf16x8 b1 = *(const bf16x8*)(kp + 32);
    sa[nt] = __builtin_amdgcn_mfma_f32_16x16x32_bf16(aq0, b0, sa[nt], 0, 0, 0);
    sa[nt] = __builtin_amdgcn_mfma_f32_16x16x32_bf16(aq1, b1, sa[nt], 0, 0, 0);
  }

  // softmax per q-row (rows live in 16-lane quads), write normalized P bf16
  #pragma unroll
  for (int i = 0; i < 4; ++i) {
    float v[17];
    #pragma unroll
    for (int nt = 0; nt < 17; ++nt) v[nt] = sa[nt][i] * 0.125f;
    float mx = -1e30f;
    #pragma unroll
    for (int nt = 0; nt < 16; ++nt) mx = fmaxf(mx, v[nt]);
    if (ln < 2) mx = fmaxf(mx, v[16]);
    #pragma unroll
    for (int m = 1; m < 16; m <<= 1) mx = fmaxf(mx, __shfl_xor(mx, m));
    float sum = 0.f;
    #pragma unroll
    for (int nt = 0; nt < 17; ++nt) {
      float e = (nt == 16 && ln >= 2) ? 0.f : __expf(v[nt] - mx);
      v[nt] = e;
      sum += e;
    }
    #pragma unroll
    for (int m = 1; m < 16; m <<= 1) sum += __shfl_xor(sum, m);
    float is = 1.f / sum;
    const int row = w * 16 + qd * 4 + i;
    #pragma unroll
    for (int nt = 0; nt < 17; ++nt)
      if (nt < 16 || ln < 2)
        Ps[row][nt * 16 + ln] = __float2bfloat16(v[nt] * is);
  }

  // O = P V : MFMA over seq keys 0..255 (V^T frags straight from global)
  f32x4 oa[4] = {};
  #pragma unroll
  for (int k0 = 0; k0 < 8; ++k0) {
    bf16x8 ap = *(const bf16x8*)&Ps[w * 16 + ln][k0 * 32 + qd * 8];
    #pragma unroll
    for (int nt = 0; nt < 4; ++nt) {
      const __hip_bfloat16* vp = vtb + (size_t)(h * DH_ + nt * 16 + ln) * TP_
                               + BASE_ + b * L_ + k0 * 32 + qd * 8;
      bf16x8 bv = *(const bf16x8*)vp;
      oa[nt] = __builtin_amdgcn_mfma_f32_16x16x32_bf16(ap, bv, oa[nt], 0, 0, 0);
    }
  }
  // + memory-key tail (keys 256,257) via VALU
  {
    float p0[4], p1[4];
    #pragma unroll
    for (int i = 0; i < 4; ++i) {
      p0[i] = __bfloat162float(Ps[w * 16 + qd * 4 + i][256]);
      p1[i] = __bfloat162float(Ps[w * 16 + qd * 4 + i][257]);
    }
    #pragma unroll
    for (int nt = 0; nt < 4; ++nt) {
      const __hip_bfloat16* vp = vtb + (size_t)(h * DH_ + nt * 16 + ln) * TP_ + b * M_;
      float v0 = __bfloat162float(vp[0]);
      float v1 = __bfloat162float(vp[1]);
      #pragma unroll
      for (int i = 0; i < 4; ++i) oa[nt][i] += p0[i] * v0 + p1[i] * v1;
    }
  }

  // write ctx (valid q rows only)
  #pragma unroll
  for (int i = 0; i < 4; ++i) {
    int j = qt * 64 + w * 16 + qd * 4 + i;
    if (j < KK_) {
      int tok = (j < 256) ? (BASE_ + b * L_ + j) : (b * M_ + (j - 256));
      #pragma unroll
      for (int nt = 0; nt < 4; ++nt)
        ctx[(size_t)tok * D_ + h * DH_ + nt * 16 + ln] = oa[nt][i];
    }
  }
}

// ---------------------------------------------------------------------------
__global__ __launch_bounds__(256) void add_ln_kernel(
    float* __restrict__ x, const float* __restrict__ delta,
    const float* __restrict__ g, const float* __restrict__ b,
    __hip_bfloat16* __restrict__ xb) {
  __shared__ float sred[4];
  __shared__ float sbc;
  const int t = blockIdx.x, tid = threadIdx.x;
  float y[3];
  float s = 0.f;
  #pragma unroll
  for (int i = 0; i < 3; ++i) {
    int d = tid + i * 256;
    y[i] = x[(long long)t * D_ + d] + delta[(long long)t * D_ + d];
    s += y[i];
  }
  #pragma unroll
  for (int o = 32; o > 0; o >>= 1) s += __shfl_down(s, o);
  if ((tid & 63) == 0) sred[tid >> 6] = s;
  __syncthreads();
  if (tid == 0) sbc = (sred[0] + sred[1] + sred[2] + sred[3]) * (1.f / D_);
  __syncthreads();
  const float mu = sbc;
  __syncthreads();
  float vs = 0.f;
  #pragma unroll
  for (int i = 0; i < 3; ++i) { float d = y[i] - mu; vs += d * d; }
  #pragma unroll
  for (int o = 32; o > 0; o >>= 1) vs += __shfl_down(vs, o);
  if ((tid & 63) == 0) sred[tid >> 6] = vs;
  __syncthreads();
  if (tid == 0) sbc = (sred[0] + sred[1] + sred[2] + sred[3]) * (1.f / D_);
  __syncthreads();
  const float inv = rsqrtf(sbc + 1e-5f);
  #pragma unroll
  for (int i = 0; i < 3; ++i) {
    int d = tid + i * 256;
    float v = (y[i] - mu) * inv * g[d] + b[d];
    x[(long long)t * D_ + d]  = v;
    xb[(long long)t * D_ + d] = __float2bfloat16(v);
  }
}

__global__ __launch_bounds__(256) void out_copy_kernel(
    const float* __restrict__ x, float* __restrict__ out, int n) {
  int i = blockIdx.x * 256 + threadIdx.x;
  if (i < n) out[i] = x[BASE_ * D_ + i];
}

// ---------------------------------------------------------------------------
extern "C" void kernel_launch(void* const* d_in, const int* in_sizes, int n_in,
                              void* d_out, int out_size, void* d_ws, size_t ws_size,
                              hipStream_t stream) {
  const int*   ids    = (const int*)  d_in[0];
  const float* memory = (const float*)d_in[1];
  const float* emb    = (const float*)d_in[2];
  const float* pos    = (const float*)d_in[3];
  const float* Wq     = (const float*)d_in[4];
  const float* bq     = (const float*)d_in[5];
  const float* Wk     = (const float*)d_in[6];
  const float* bk     = (const float*)d_in[7];
  const float* Wv     = (const float*)d_in[8];
  const float* bv     = (const float*)d_in[9];
  const float* W1     = (const float*)d_in[10];
  const float* b1     = (const float*)d_in[11];
  const float* W2     = (const float*)d_in[12];
  const float* b2     = (const float*)d_in[13];
  const float* g1     = (const float*)d_in[14];
  const float* be1    = (const float*)d_in[15];
  const float* g2     = (const float*)d_in[16];
  const float* be2    = (const float*)d_in[17];

  char* w = (char*)d_ws;
  float* x    = (float*)w;                      w += (size_t)TP_ * D_ * 4;
  float* cb   = (float*)w;                      w += (size_t)TP_ * D_ * 4;
  float* bqkv = (float*)w;                      w += (size_t)LAYERS_ * QS_ * 4;
  __hip_bfloat16* xb    = (__hip_bfloat16*)w;   w += (size_t)TP_ * D_ * 2;
  __hip_bfloat16* qkvb  = (__hip_bfloat16*)w;   w += (size_t)TP_ * QS_ * 2;
  __hip_bfloat16* vtb   = (__hip_bfloat16*)w;   w += (size_t)D_ * TP_ * 2;
  __hip_bfloat16* hbb   = (__hip_bfloat16*)w;   w += (size_t)TP_ * FF_ * 2;
  __hip_bfloat16* Wqkvt = (__hip_bfloat16*)w;   w += (size_t)LAYERS_ * QS_ * D_ * 2;
  __hip_bfloat16* W1t   = (__hip_bfloat16*)w;   w += (size_t)LAYERS_ * FF_ * D_ * 2;
  __hip_bfloat16* W2t   = (__hip_bfloat16*)w;   w += (size_t)LAYERS_ * D_ * FF_ * 2;

  for (int i = 0; i < LAYERS_; ++i) {
    const size_t wo  = (size_t)i * D_ * D_;
    const size_t wo1 = (size_t)i * D_ * FF_;
    __hip_bfloat16* dqkv = Wqkvt + (size_t)i * QS_ * D_;
    transpose_cast_kernel<<<dim3(D_ / 32, D_ / 32), 256, 0, stream>>>(Wq + wo, dqkv,                       D_, D_);
    transpose_cast_kernel<<<dim3(D_ / 32, D_ / 32), 256, 0, stream>>>(Wk + wo, dqkv + (size_t)D_ * D_,     D_, D_);
    transpose_cast_kernel<<<dim3(D_ / 32, D_ / 32), 256, 0, stream>>>(Wv + wo, dqkv + (size_t)2 * D_ * D_, D_, D_);
    transpose_cast_kernel<<<dim3(FF_ / 32, D_ / 32), 256, 0, stream>>>(W1 + wo1, W1t + (size_t)i * FF_ * D_, D_, FF_);
    transpose_cast_kernel<<<dim3(D_ / 32, FF_ / 32), 256, 0, stream>>>(W2 + wo1, W2t + (size_t)i * D_ * FF_, FF_, D_);
  }
  pack_bias_kernel<<<LAYERS_ * QS_ / 256, 256, 0, stream>>>(bq, bk, bv, bqkv);

  embed_kernel<<<T_, 256, 0, stream>>>(ids, memory, emb, pos, x, xb);

  for (int i = 0; i < LAYERS_; ++i) {
    gemm_mfma<0, 0, 1, 1><<<dim3(QS_ / 64, TP_ / 64), 256, 0, stream>>>(
        xb, Wqkvt + (size_t)i * QS_ * D_, bqkv + i * QS_, nullptr, qkvb, vtb, QS_, D_);
    attn_mfma<<<dim3(5, H_, N_), 256, 0, stream>>>(qkvb, vtb, cb);
    add_ln_kernel<<<T_, 256, 0, stream>>>(x, cb, g1 + i * D_, be1 + i * D_, xb);
    gemm_mfma<1, 0, 1, 0><<<dim3(FF_ / 64, TP_ / 64), 256, 0, stream>>>(
        xb, W1t + (size_t)i * FF_ * D_, b1 + i * FF_, nullptr, hbb, nullptr, FF_, D_);
    gemm_mfma<0, 1, 0, 0><<<dim3(D_ / 64, TP_ / 64), 256, 0, stream>>>(
        hbb, W2t + (size_t)i * D_ * FF_, b2 + i * D_, cb, nullptr, nullptr, D_, FF_);
    add_ln_kernel<<<T_, 256, 0, stream>>>(x, cb, g2 + i * D_, be2 + i * D_, xb);
  }

  out_copy_kernel<<<(out_size + 255) / 256, 256, 0, stream>>>(x, (float*)d_out, out_size);
}